// Round 17
// baseline (255.972 us; speedup 1.0000x reference)
//
#include <hip/hip_runtime.h>
#include <math.h>

#define NN   50000
#define NE   800000
#define NG   500
#define FIN  80
#define FOUT 40
#define HH   20
#define NC   5

// -------- workspace layout (float offsets) --------
#define OFF_DEG    0               // f32[NN] -> dinv in place (after scanptr)
#define OFF_CNT    50000           // u32[NN]
#define OFF_POOLED 100000          // f32[NG*FOUT]
#define OFF_SEQ    120000          // f32[NG*HH]
#define OFF_ROWPTR 130000          // u32[NN+1] (+pad)
#define OFF_RANK   180004          // u32[NE]
#define OFF_REC    980004          // uint2[NE] (8B-aligned)
#define OFF_Y      2580004         // bf16[NN*FOUT] = 4 MB (8B-aligned)
#define OFF_PRE    3580004         // f32[NG*HH] (pre-scaled by 2log2e)

#define TWO_LOG2E 2.8853900817779268f

// tanh from PRE-SCALED input y = 2*log2e*x : 1 - 2/(exp2(y)+1)
__device__ __forceinline__ float tanh_pre(float y) {
    float e;
    asm("v_exp_f32 %0, %1" : "=v"(e) : "v"(y));
    float r;
    asm("v_rcp_f32 %0, %1" : "=v"(r) : "v"(e + 1.0f));
    return fmaf(-2.0f, r, 1.0f);
}

__device__ __forceinline__ float bcast_lane(float v, int k) {
    return __uint_as_float(__builtin_amdgcn_readlane(__float_as_uint(v), k));
}

__device__ __forceinline__ unsigned short bf16_rn(float f) {
    unsigned u = __float_as_uint(f);
    return (unsigned short)((u + 0x7fffu + ((u >> 16) & 1u)) >> 16);
}
__device__ __forceinline__ float bf16_to_f32(unsigned short h) {
    return __uint_as_float((unsigned)h << 16);
}

// ---- deg[src] += w ; rank[e] = cnt[dst]++ ----
__global__ void k_degcnt(const int* __restrict__ ei, const float* __restrict__ w,
                         float* __restrict__ deg, unsigned int* __restrict__ cnt,
                         unsigned int* __restrict__ rank) {
    int e = blockIdx.x * 256 + threadIdx.x;
    if (e < NE) {
        atomicAdd(&deg[ei[e]], w[e]);
        rank[e] = atomicAdd(&cnt[ei[NE + e]], 1u);
    }
}

// ---- y = bf16(x @ W1) (unscaled) ----
__global__ void k_y(const float* __restrict__ x, const float* __restrict__ W1,
                    unsigned short* __restrict__ y) {
    int gid = blockIdx.x * 256 + threadIdx.x;
    if (gid >= NN * 10) return;
    int n = gid / 10;
    int c = gid % 10;
    const float* xr = x + (size_t)n * FIN;
    float a0 = 0.f, a1 = 0.f, a2 = 0.f, a3 = 0.f;
    #pragma unroll 8
    for (int f = 0; f < FIN; ++f) {
        float xf = xr[f];
        const float4 wv = *reinterpret_cast<const float4*>(W1 + f * FOUT + c * 4);
        a0 = fmaf(xf, wv.x, a0); a1 = fmaf(xf, wv.y, a1);
        a2 = fmaf(xf, wv.z, a2); a3 = fmaf(xf, wv.w, a3);
    }
    ushort4 o;
    o.x = bf16_rn(a0); o.y = bf16_rn(a1); o.z = bf16_rn(a2); o.w = bf16_rn(a3);
    *reinterpret_cast<ushort4*>(y + (size_t)gid * 4) = o;
}

// ---- block 0: exclusive scan of cnt -> rowptr; blocks 1..49: dinv in place ----
__global__ void k_scanptr(const unsigned int* __restrict__ cnt,
                          unsigned int* __restrict__ rowptr,
                          float* __restrict__ deg) {
    int tid = threadIdx.x;
    if (blockIdx.x > 0) {
        int n = (blockIdx.x - 1) * 1024 + tid;
        if (n < NN) {
            float d = deg[n];
            deg[n] = (d > 0.f) ? rsqrtf(d) : 0.f;
        }
        return;
    }
    __shared__ unsigned int tot[1024];
    bool act = tid < 1000;
    int beg = tid * 50;
    unsigned int vals[50];
    if (act) {
        const uint2* c2 = reinterpret_cast<const uint2*>(cnt + beg);
        #pragma unroll
        for (int j = 0; j < 25; ++j) {
            uint2 v = c2[j];
            vals[j * 2 + 0] = v.x;
            vals[j * 2 + 1] = v.y;
        }
    }
    unsigned int s = 0;
    if (act) {
        #pragma unroll
        for (int j = 0; j < 50; ++j) s += vals[j];
    }
    tot[tid] = s;
    __syncthreads();
    for (int off = 1; off < 1024; off <<= 1) {
        unsigned int t = (tid >= off) ? tot[tid - off] : 0u;
        __syncthreads();
        tot[tid] += t;
        __syncthreads();
    }
    unsigned int base = (tid > 0) ? tot[tid - 1] : 0u;
    if (act) {
        #pragma unroll
        for (int j = 0; j < 50; ++j) {
            unsigned int v = vals[j];
            vals[j] = base;
            base += v;
        }
        uint2* r2 = reinterpret_cast<uint2*>(rowptr + beg);
        #pragma unroll
        for (int j = 0; j < 25; ++j)
            r2[j] = make_uint2(vals[j * 2 + 0], vals[j * 2 + 1]);
    }
    if (tid == 1023) rowptr[NN] = tot[1023];
}

// ---- fill CSR (NO atomics, ONE 8B store): rec[rowptr[d]+rank[e]] = {src, -dinv_s*w*dinv_d} ----
__global__ void k_fill(const int* __restrict__ ei, const float* __restrict__ w,
                       const float* __restrict__ dinv,
                       const unsigned int* __restrict__ rowptr,
                       const unsigned int* __restrict__ rank,
                       uint2* __restrict__ rec) {
    int e = blockIdx.x * 256 + threadIdx.x;
    if (e >= NE) return;
    int s = ei[e];
    int d = ei[NE + e];
    float nm = -dinv[s] * w[e] * dinv[d];   // dinv: 200KB, L2-resident
    unsigned int pos = rowptr[d] + rank[e];
    rec[pos] = make_uint2((unsigned int)s, __float_as_uint(nm));
}

// ---- gather z = sum nm*y[src]; h = relu(x@W0 + b + z); LDS pool ----
__global__ void k_gather_h(const unsigned int* __restrict__ rowptr,
                           const uint2* __restrict__ rec,
                           const unsigned short* __restrict__ y,
                           const float* __restrict__ x,
                           const float* __restrict__ W0,
                           const float* __restrict__ bconv,
                           const int* __restrict__ batch,
                           float* __restrict__ pooled) {
    __shared__ float lpool[32 * FOUT];
    int tid = threadIdx.x;
    int b0 = blockIdx.x * 256;
    #pragma unroll
    for (int i = tid; i < 32 * FOUT; i += 256) lpool[i] = 0.f;
    int g_lo = batch[b0 / 10];
    __syncthreads();

    int gid = b0 + tid;
    if (gid < NN * 10) {
        int n = gid / 10;
        int c = gid % 10;
        unsigned int beg = rowptr[n], end = rowptr[n + 1];
        float z0 = 0.f, z1 = 0.f, z2 = 0.f, z3 = 0.f;
        const ushort4* y4 = reinterpret_cast<const ushort4*>(y);
        for (unsigned int k = beg; k < end; ++k) {
            uint2 r = rec[k];
            float nm = __uint_as_float(r.y);
            ushort4 yv = y4[r.x * 10 + c];
            z0 = fmaf(nm, bf16_to_f32(yv.x), z0);
            z1 = fmaf(nm, bf16_to_f32(yv.y), z1);
            z2 = fmaf(nm, bf16_to_f32(yv.z), z2);
            z3 = fmaf(nm, bf16_to_f32(yv.w), z3);
        }
        const float4 bv = *reinterpret_cast<const float4*>(bconv + c * 4);
        float a0 = bv.x + z0, a1 = bv.y + z1, a2 = bv.z + z2, a3 = bv.w + z3;
        const float* xr = x + (size_t)n * FIN;
        #pragma unroll 8
        for (int f = 0; f < FIN; ++f) {
            float xf = xr[f];
            const float4 wv = *reinterpret_cast<const float4*>(W0 + f * FOUT + c * 4);
            a0 = fmaf(xf, wv.x, a0); a1 = fmaf(xf, wv.y, a1);
            a2 = fmaf(xf, wv.z, a2); a3 = fmaf(xf, wv.w, a3);
        }
        float h0 = fmaxf(a0, 0.f);
        float h1 = fmaxf(a1, 0.f);
        float h2 = fmaxf(a2, 0.f);
        float h3 = fmaxf(a3, 0.f);
        float* lp = lpool + (batch[n] - g_lo) * FOUT + c * 4;
        atomicAdd(lp + 0, h0);
        atomicAdd(lp + 1, h1);
        atomicAdd(lp + 2, h2);
        atomicAdd(lp + 3, h3);
    }
    __syncthreads();
    int n_hi = (b0 + 255) / 10;
    if (n_hi > NN - 1) n_hi = NN - 1;
    int span = batch[n_hi] - g_lo + 1;
    for (int i = tid; i < span * FOUT; i += 256) {
        float v = lpool[i];
        if (v != 0.f) atomicAdd(&pooled[(size_t)g_lo * FOUT + i], v);
    }
}

// ---- pre[t][j] = 2log2e*(pooled[t]·W_ih[j] + b_ih[j] + b_hh[j]) ----
__global__ void k_pre(const float* __restrict__ pooled, const float* __restrict__ Wih,
                      const float* __restrict__ bih, const float* __restrict__ bhh,
                      float* __restrict__ pre) {
    int gid = blockIdx.x * 256 + threadIdx.x;
    if (gid >= NG * HH) return;
    int t = gid / HH;
    int j = gid % HH;
    float acc = bih[j] + bhh[j];
    const float* pr = pooled + t * FOUT;
    const float* wr = Wih + j * FOUT;
    #pragma unroll
    for (int f = 0; f < FOUT; ++f) acc = fmaf(pr[f], wr[f], acc);
    pre[gid] = acc * TWO_LOG2E;
}

// ---- tail: copy pre->LDS -> wave-0 serial scan -> fc+log_softmax ----
__global__ void k_tail(const float* __restrict__ pre, const float* __restrict__ Whh,
                       const float* __restrict__ Wfc, const float* __restrict__ bfc,
                       float* __restrict__ seq, float* __restrict__ out) {
    __shared__ float spre[NG * HH];          // 40 KB (pre-scaled)
    int tid = threadIdx.x;

    {
        const float4* p4 = reinterpret_cast<const float4*>(pre);
        float4* s4 = reinterpret_cast<float4*>(spre);
        for (int i = tid; i < NG * HH / 4; i += 1024) s4[i] = p4[i];
    }
    __syncthreads();

    if (tid < 64) {
        int lane = tid;
        float whh[HH];
        #pragma unroll
        for (int k = 0; k < HH; ++k)
            whh[k] = (lane < HH) ? Whh[lane * HH + k] * TWO_LOG2E : 0.f;
        int myoff = (lane < HH) ? lane : 0;
        float h = 0.f;
        float pre_cur = spre[myoff];
        for (int t = 0; t < NG; ++t) {
            int nt = (t + 1 < NG) ? t + 1 : t;
            float pre_next = spre[nt * HH + myoff];
            float hv[HH];
            #pragma unroll
            for (int k = 0; k < HH; ++k) hv[k] = bcast_lane(h, k);
            float a0 = pre_cur, a1 = 0.f, a2 = 0.f, a3 = 0.f;
            #pragma unroll
            for (int k = 0; k < HH; k += 4) {
                a0 = fmaf(hv[k + 0], whh[k + 0], a0);
                a1 = fmaf(hv[k + 1], whh[k + 1], a1);
                a2 = fmaf(hv[k + 2], whh[k + 2], a2);
                a3 = fmaf(hv[k + 3], whh[k + 3], a3);
            }
            h = tanh_pre((a0 + a1) + (a2 + a3));
            if (lane < HH) seq[t * HH + lane] = h;
            pre_cur = pre_next;
        }
    }
    __syncthreads();

    if (tid < NG) {
        float s[HH];
        #pragma unroll
        for (int j = 0; j < HH; ++j) s[j] = seq[tid * HH + j];
        float lg[NC];
        float m = -1e30f;
        #pragma unroll
        for (int c = 0; c < NC; ++c) {
            float acc = bfc[c];
            #pragma unroll
            for (int j = 0; j < HH; ++j) acc = fmaf(s[j], Wfc[c * HH + j], acc);
            lg[c] = acc;
            m = fmaxf(m, acc);
        }
        float lse = 0.f;
        #pragma unroll
        for (int c = 0; c < NC; ++c) lse += expf(lg[c] - m);
        lse = logf(lse);
        #pragma unroll
        for (int c = 0; c < NC; ++c) out[tid * NC + c] = lg[c] - m - lse;
    }
}

extern "C" void kernel_launch(void* const* d_in, const int* in_sizes, int n_in,
                              void* d_out, int out_size, void* d_ws, size_t ws_size,
                              hipStream_t stream) {
    const float* x     = (const float*)d_in[0];
    const int*   ei    = (const int*)  d_in[1];
    const float* w     = (const float*)d_in[2];
    const int*   batch = (const int*)  d_in[3];
    const float* W0    = (const float*)d_in[5];
    const float* W1    = (const float*)d_in[6];
    const float* bconv = (const float*)d_in[7];
    const float* Wih   = (const float*)d_in[8];
    const float* Whh   = (const float*)d_in[9];
    const float* bih   = (const float*)d_in[10];
    const float* bhh   = (const float*)d_in[11];
    const float* Wfc   = (const float*)d_in[12];
    const float* bfc   = (const float*)d_in[13];
    float* out = (float*)d_out;

    float*          ws     = (float*)d_ws;
    float*          deg    = ws + OFF_DEG;          // -> dinv in place
    unsigned int*   cnt    = (unsigned int*)(ws + OFF_CNT);
    float*          pooled = ws + OFF_POOLED;
    float*          seq    = ws + OFF_SEQ;
    unsigned int*   rowptr = (unsigned int*)(ws + OFF_ROWPTR);
    unsigned int*   rank   = (unsigned int*)(ws + OFF_RANK);
    uint2*          rec    = (uint2*)(ws + OFF_REC);
    unsigned short* y      = (unsigned short*)(ws + OFF_Y);
    float*          pre    = ws + OFF_PRE;

    // zero deg | cnt | pooled (contiguous, 480 KB)
    hipMemsetAsync(d_ws, 0, (size_t)(OFF_POOLED + NG * FOUT) * sizeof(float), stream);

    k_degcnt<<<(NE + 255) / 256, 256, 0, stream>>>(ei, w, deg, cnt, rank);
    k_y<<<(NN * 10 + 255) / 256, 256, 0, stream>>>(x, W1, y);
    k_scanptr<<<50, 1024, 0, stream>>>(cnt, rowptr, deg);   // blk0 scan, blk1-49 dinv
    k_fill<<<(NE + 255) / 256, 256, 0, stream>>>(ei, w, deg, rowptr, rank, rec);
    k_gather_h<<<(NN * 10 + 255) / 256, 256, 0, stream>>>(rowptr, rec, y, x,
                                                          W0, bconv, batch, pooled);
    k_pre<<<(NG * HH + 255) / 256, 256, 0, stream>>>(pooled, Wih, bih, bhh, pre);
    k_tail<<<1, 1024, 0, stream>>>(pre, Whh, Wfc, bfc, seq, out);
}

// Round 18
// 224.800 us; speedup vs baseline: 1.1387x; 1.1387x over previous
//
#include <hip/hip_runtime.h>
#include <math.h>

#define NN   50000
#define NE   800000
#define NG   500
#define FIN  80
#define FOUT 40
#define HH   20
#define NC   5

#define NB_EDGE 3125               // ceil(NE/256)
#define NB_Y    1954               // ceil(NN*10/256)

// -------- workspace layout (float offsets) --------
#define OFF_DEG    0               // f32[NN] -> dinv in place (after scanptr)
#define OFF_CNT    50000           // u32[NN]
#define OFF_POOLED 100000          // f32[NG*FOUT]
#define OFF_SEQ    120000          // f32[NG*HH]
#define OFF_ROWPTR 130000          // u32[NN+1] (+pad)
#define OFF_RANK   180004          // u32[NE]
#define OFF_REC    980004          // uint2[NE] (8B-aligned)
#define OFF_Y      2580004         // bf16[NN*FOUT] = 4 MB (8B-aligned)
#define OFF_PRE    3580004         // f32[NG*HH] (pre-scaled by 2log2e)

#define TWO_LOG2E 2.8853900817779268f

// tanh from PRE-SCALED input y = 2*log2e*x : 1 - 2/(exp2(y)+1)
__device__ __forceinline__ float tanh_pre(float y) {
    float e;
    asm("v_exp_f32 %0, %1" : "=v"(e) : "v"(y));
    float r;
    asm("v_rcp_f32 %0, %1" : "=v"(r) : "v"(e + 1.0f));
    return fmaf(-2.0f, r, 1.0f);
}

__device__ __forceinline__ float bcast_lane(float v, int k) {
    return __uint_as_float(__builtin_amdgcn_readlane(__float_as_uint(v), k));
}

__device__ __forceinline__ unsigned short bf16_rn(float f) {
    unsigned u = __float_as_uint(f);
    return (unsigned short)((u + 0x7fffu + ((u >> 16) & 1u)) >> 16);
}
__device__ __forceinline__ float bf16_to_f32(unsigned short h) {
    return __uint_as_float((unsigned)h << 16);
}

// ---- megakernel, INTERLEAVED: first 2*NB_Y blocks alternate edge/y so the
//      VALU-dense y blocks are co-resident with atomic-stalled edge blocks
//      from dispatch 0; remaining blocks are all edge. ----
__global__ void k_degcnt_y(const int* __restrict__ ei, const float* __restrict__ w,
                           float* __restrict__ deg, unsigned int* __restrict__ cnt,
                           unsigned int* __restrict__ rank,
                           const float* __restrict__ x, const float* __restrict__ W1,
                           unsigned short* __restrict__ y) {
    int b = blockIdx.x;
    int tid = threadIdx.x;
    bool is_edge;
    int wb;                         // work-block index within its type
    if (b < 2 * NB_Y) {
        is_edge = (b & 1) == 0;
        wb = b >> 1;
    } else {
        is_edge = true;
        wb = b - NB_Y;              // NB_Y..NB_EDGE-1
    }
    if (is_edge) {
        int e = wb * 256 + tid;
        if (e < NE) {
            atomicAdd(&deg[ei[e]], w[e]);
            rank[e] = atomicAdd(&cnt[ei[NE + e]], 1u);
        }
        return;
    }
    int gid = wb * 256 + tid;
    if (gid >= NN * 10) return;
    int n = gid / 10;
    int c = gid % 10;
    const float* xr = x + (size_t)n * FIN;
    float a0 = 0.f, a1 = 0.f, a2 = 0.f, a3 = 0.f;
    #pragma unroll 8
    for (int f = 0; f < FIN; ++f) {
        float xf = xr[f];
        const float4 wv = *reinterpret_cast<const float4*>(W1 + f * FOUT + c * 4);
        a0 = fmaf(xf, wv.x, a0); a1 = fmaf(xf, wv.y, a1);
        a2 = fmaf(xf, wv.z, a2); a3 = fmaf(xf, wv.w, a3);
    }
    ushort4 o;
    o.x = bf16_rn(a0); o.y = bf16_rn(a1); o.z = bf16_rn(a2); o.w = bf16_rn(a3);
    *reinterpret_cast<ushort4*>(y + (size_t)gid * 4) = o;
}

// ---- block 0: exclusive scan of cnt -> rowptr; blocks 1..49: dinv in place ----
__global__ void k_scanptr(const unsigned int* __restrict__ cnt,
                          unsigned int* __restrict__ rowptr,
                          float* __restrict__ deg) {
    int tid = threadIdx.x;
    if (blockIdx.x > 0) {
        int n = (blockIdx.x - 1) * 1024 + tid;
        if (n < NN) {
            float d = deg[n];
            deg[n] = (d > 0.f) ? rsqrtf(d) : 0.f;
        }
        return;
    }
    __shared__ unsigned int tot[1024];
    bool act = tid < 1000;
    int beg = tid * 50;
    unsigned int vals[50];
    if (act) {
        const uint2* c2 = reinterpret_cast<const uint2*>(cnt + beg);
        #pragma unroll
        for (int j = 0; j < 25; ++j) {
            uint2 v = c2[j];
            vals[j * 2 + 0] = v.x;
            vals[j * 2 + 1] = v.y;
        }
    }
    unsigned int s = 0;
    if (act) {
        #pragma unroll
        for (int j = 0; j < 50; ++j) s += vals[j];
    }
    tot[tid] = s;
    __syncthreads();
    for (int off = 1; off < 1024; off <<= 1) {
        unsigned int t = (tid >= off) ? tot[tid - off] : 0u;
        __syncthreads();
        tot[tid] += t;
        __syncthreads();
    }
    unsigned int base = (tid > 0) ? tot[tid - 1] : 0u;
    if (act) {
        #pragma unroll
        for (int j = 0; j < 50; ++j) {
            unsigned int v = vals[j];
            vals[j] = base;
            base += v;
        }
        uint2* r2 = reinterpret_cast<uint2*>(rowptr + beg);
        #pragma unroll
        for (int j = 0; j < 25; ++j)
            r2[j] = make_uint2(vals[j * 2 + 0], vals[j * 2 + 1]);
    }
    if (tid == 1023) rowptr[NN] = tot[1023];
}

// ---- fill CSR (NO atomics, ONE 8B store): rec[rowptr[d]+rank[e]] = {src, -dinv_s*w*dinv_d} ----
__global__ void k_fill(const int* __restrict__ ei, const float* __restrict__ w,
                       const float* __restrict__ dinv,
                       const unsigned int* __restrict__ rowptr,
                       const unsigned int* __restrict__ rank,
                       uint2* __restrict__ rec) {
    int e = blockIdx.x * 256 + threadIdx.x;
    if (e >= NE) return;
    int s = ei[e];
    int d = ei[NE + e];
    float nm = -dinv[s] * w[e] * dinv[d];   // dinv: 200KB, L2-resident
    unsigned int pos = rowptr[d] + rank[e];
    rec[pos] = make_uint2((unsigned int)s, __float_as_uint(nm));
}

// ---- gather z = sum nm*y[src]; h = relu(x@W0 + b + z); LDS pool ----
__global__ void k_gather_h(const unsigned int* __restrict__ rowptr,
                           const uint2* __restrict__ rec,
                           const unsigned short* __restrict__ y,
                           const float* __restrict__ x,
                           const float* __restrict__ W0,
                           const float* __restrict__ bconv,
                           const int* __restrict__ batch,
                           float* __restrict__ pooled) {
    __shared__ float lpool[32 * FOUT];
    int tid = threadIdx.x;
    int b0 = blockIdx.x * 256;
    #pragma unroll
    for (int i = tid; i < 32 * FOUT; i += 256) lpool[i] = 0.f;
    int g_lo = batch[b0 / 10];
    __syncthreads();

    int gid = b0 + tid;
    if (gid < NN * 10) {
        int n = gid / 10;
        int c = gid % 10;
        unsigned int beg = rowptr[n], end = rowptr[n + 1];
        float z0 = 0.f, z1 = 0.f, z2 = 0.f, z3 = 0.f;
        const ushort4* y4 = reinterpret_cast<const ushort4*>(y);
        for (unsigned int k = beg; k < end; ++k) {
            uint2 r = rec[k];
            float nm = __uint_as_float(r.y);
            ushort4 yv = y4[r.x * 10 + c];
            z0 = fmaf(nm, bf16_to_f32(yv.x), z0);
            z1 = fmaf(nm, bf16_to_f32(yv.y), z1);
            z2 = fmaf(nm, bf16_to_f32(yv.z), z2);
            z3 = fmaf(nm, bf16_to_f32(yv.w), z3);
        }
        const float4 bv = *reinterpret_cast<const float4*>(bconv + c * 4);
        float a0 = bv.x + z0, a1 = bv.y + z1, a2 = bv.z + z2, a3 = bv.w + z3;
        const float* xr = x + (size_t)n * FIN;
        #pragma unroll 8
        for (int f = 0; f < FIN; ++f) {
            float xf = xr[f];
            const float4 wv = *reinterpret_cast<const float4*>(W0 + f * FOUT + c * 4);
            a0 = fmaf(xf, wv.x, a0); a1 = fmaf(xf, wv.y, a1);
            a2 = fmaf(xf, wv.z, a2); a3 = fmaf(xf, wv.w, a3);
        }
        float h0 = fmaxf(a0, 0.f);
        float h1 = fmaxf(a1, 0.f);
        float h2 = fmaxf(a2, 0.f);
        float h3 = fmaxf(a3, 0.f);
        float* lp = lpool + (batch[n] - g_lo) * FOUT + c * 4;
        atomicAdd(lp + 0, h0);
        atomicAdd(lp + 1, h1);
        atomicAdd(lp + 2, h2);
        atomicAdd(lp + 3, h3);
    }
    __syncthreads();
    int n_hi = (b0 + 255) / 10;
    if (n_hi > NN - 1) n_hi = NN - 1;
    int span = batch[n_hi] - g_lo + 1;
    for (int i = tid; i < span * FOUT; i += 256) {
        float v = lpool[i];
        if (v != 0.f) atomicAdd(&pooled[(size_t)g_lo * FOUT + i], v);
    }
}

// ---- pre[t][j] = 2log2e*(pooled[t]·W_ih[j] + b_ih[j] + b_hh[j]) ----
__global__ void k_pre(const float* __restrict__ pooled, const float* __restrict__ Wih,
                      const float* __restrict__ bih, const float* __restrict__ bhh,
                      float* __restrict__ pre) {
    int gid = blockIdx.x * 256 + threadIdx.x;
    if (gid >= NG * HH) return;
    int t = gid / HH;
    int j = gid % HH;
    float acc = bih[j] + bhh[j];
    const float* pr = pooled + t * FOUT;
    const float* wr = Wih + j * FOUT;
    #pragma unroll
    for (int f = 0; f < FOUT; ++f) acc = fmaf(pr[f], wr[f], acc);
    pre[gid] = acc * TWO_LOG2E;
}

// ---- tail: copy pre->LDS -> wave-0 serial scan -> fc+log_softmax ----
__global__ void k_tail(const float* __restrict__ pre, const float* __restrict__ Whh,
                       const float* __restrict__ Wfc, const float* __restrict__ bfc,
                       float* __restrict__ seq, float* __restrict__ out) {
    __shared__ float spre[NG * HH];          // 40 KB (pre-scaled)
    int tid = threadIdx.x;

    {
        const float4* p4 = reinterpret_cast<const float4*>(pre);
        float4* s4 = reinterpret_cast<float4*>(spre);
        for (int i = tid; i < NG * HH / 4; i += 1024) s4[i] = p4[i];
    }
    __syncthreads();

    if (tid < 64) {
        int lane = tid;
        float whh[HH];
        #pragma unroll
        for (int k = 0; k < HH; ++k)
            whh[k] = (lane < HH) ? Whh[lane * HH + k] * TWO_LOG2E : 0.f;
        int myoff = (lane < HH) ? lane : 0;
        float h = 0.f;
        float pre_cur = spre[myoff];
        for (int t = 0; t < NG; ++t) {
            int nt = (t + 1 < NG) ? t + 1 : t;
            float pre_next = spre[nt * HH + myoff];
            float hv[HH];
            #pragma unroll
            for (int k = 0; k < HH; ++k) hv[k] = bcast_lane(h, k);
            float a0 = pre_cur, a1 = 0.f, a2 = 0.f, a3 = 0.f;
            #pragma unroll
            for (int k = 0; k < HH; k += 4) {
                a0 = fmaf(hv[k + 0], whh[k + 0], a0);
                a1 = fmaf(hv[k + 1], whh[k + 1], a1);
                a2 = fmaf(hv[k + 2], whh[k + 2], a2);
                a3 = fmaf(hv[k + 3], whh[k + 3], a3);
            }
            h = tanh_pre((a0 + a1) + (a2 + a3));
            if (lane < HH) seq[t * HH + lane] = h;
            pre_cur = pre_next;
        }
    }
    __syncthreads();

    if (tid < NG) {
        float s[HH];
        #pragma unroll
        for (int j = 0; j < HH; ++j) s[j] = seq[tid * HH + j];
        float lg[NC];
        float m = -1e30f;
        #pragma unroll
        for (int c = 0; c < NC; ++c) {
            float acc = bfc[c];
            #pragma unroll
            for (int j = 0; j < HH; ++j) acc = fmaf(s[j], Wfc[c * HH + j], acc);
            lg[c] = acc;
            m = fmaxf(m, acc);
        }
        float lse = 0.f;
        #pragma unroll
        for (int c = 0; c < NC; ++c) lse += expf(lg[c] - m);
        lse = logf(lse);
        #pragma unroll
        for (int c = 0; c < NC; ++c) out[tid * NC + c] = lg[c] - m - lse;
    }
}

extern "C" void kernel_launch(void* const* d_in, const int* in_sizes, int n_in,
                              void* d_out, int out_size, void* d_ws, size_t ws_size,
                              hipStream_t stream) {
    const float* x     = (const float*)d_in[0];
    const int*   ei    = (const int*)  d_in[1];
    const float* w     = (const float*)d_in[2];
    const int*   batch = (const int*)  d_in[3];
    const float* W0    = (const float*)d_in[5];
    const float* W1    = (const float*)d_in[6];
    const float* bconv = (const float*)d_in[7];
    const float* Wih   = (const float*)d_in[8];
    const float* Whh   = (const float*)d_in[9];
    const float* bih   = (const float*)d_in[10];
    const float* bhh   = (const float*)d_in[11];
    const float* Wfc   = (const float*)d_in[12];
    const float* bfc   = (const float*)d_in[13];
    float* out = (float*)d_out;

    float*          ws     = (float*)d_ws;
    float*          deg    = ws + OFF_DEG;          // -> dinv in place
    unsigned int*   cnt    = (unsigned int*)(ws + OFF_CNT);
    float*          pooled = ws + OFF_POOLED;
    float*          seq    = ws + OFF_SEQ;
    unsigned int*   rowptr = (unsigned int*)(ws + OFF_ROWPTR);
    unsigned int*   rank   = (unsigned int*)(ws + OFF_RANK);
    uint2*          rec    = (uint2*)(ws + OFF_REC);
    unsigned short* y      = (unsigned short*)(ws + OFF_Y);
    float*          pre    = ws + OFF_PRE;

    // zero deg | cnt | pooled (contiguous, 480 KB)
    hipMemsetAsync(d_ws, 0, (size_t)(OFF_POOLED + NG * FOUT) * sizeof(float), stream);

    k_degcnt_y<<<NB_EDGE + NB_Y, 256, 0, stream>>>(ei, w, deg, cnt, rank, x, W1, y);
    k_scanptr<<<50, 1024, 0, stream>>>(cnt, rowptr, deg);   // blk0 scan, blk1-49 dinv
    k_fill<<<(NE + 255) / 256, 256, 0, stream>>>(ei, w, deg, rowptr, rank, rec);
    k_gather_h<<<(NN * 10 + 255) / 256, 256, 0, stream>>>(rowptr, rec, y, x,
                                                          W0, bconv, batch, pooled);
    k_pre<<<(NG * HH + 255) / 256, 256, 0, stream>>>(pooled, Wih, bih, bhh, pre);
    k_tail<<<1, 1024, 0, stream>>>(pre, Whh, Wfc, bfc, seq, out);
}